// Round 6
// baseline (21182.538 us; speedup 1.0000x reference)
//
#include <hip/hip_runtime.h>

typedef unsigned short u16;
typedef __attribute__((ext_vector_type(4))) float f32x4;
typedef __attribute__((ext_vector_type(8))) __bf16 bf16x8;
typedef __attribute__((ext_vector_type(4))) u16 u16x4;

#define TSEQ 512
#define BATCH 64
#define HDIM 256
#define KD   512          // compensated K: [Whi | Wlo]
#define GDIM 1024
#define EDIM 300
#define ELDA 304
#define TC   128          // time chunk
#define NC   4

__device__ __forceinline__ float b2f(u16 u){
  union { unsigned int i; float f; } v; v.i = ((unsigned int)u) << 16; return v.f;
}
__device__ __forceinline__ u16 f2b(float f){
  union { float f; unsigned int i; } v; v.f = f;
  unsigned int x = v.i;
  unsigned int r = (x + 0x7fffu + ((x >> 16) & 1u)) >> 16;
  return (u16)r;
}
__device__ __forceinline__ float sigm(float x){
  return __builtin_amdgcn_rcpf(1.f + __expf(-x));
}
__device__ __forceinline__ float tanh_(float x){
  float e = __expf(2.f * x);
  return 1.f - 2.f * __builtin_amdgcn_rcpf(e + 1.f);
}
__device__ __forceinline__ f32x4 mfma16(bf16x8 a, bf16x8 b, f32x4 c){
  return __builtin_amdgcn_mfma_f32_16x16x32_bf16(a, b, c, 0, 0, 0);
}

// ---------------- Wih convert (fp32 -> bf16), 4 segments ----------------
struct Cvt6 {
  const float* src[4];
  u16* dst[4];
  int cum[5];   // cumulative float4 counts
};
__global__ void k6_cvt(Cvt6 a){
  int g = blockIdx.x * 256 + threadIdx.x;
  if (g >= a.cum[4]) return;
  int s = 0;
#pragma unroll
  for (int i = 1; i < 4; ++i) if (g >= a.cum[i]) s = i;
  int off = g - a.cum[s];
  f32x4 v = *(const f32x4*)(a.src[s] + (size_t)off * 4);
  u16x4 o = { f2b(v[0]), f2b(v[1]), f2b(v[2]), f2b(v[3]) };
  *(u16x4*)(a.dst[s] + (size_t)off * 4) = o;
}

// ---------------- Whh convert: hi|lo compensated planes ----------------
// 4 matrices [1024][256] fp32 -> whh2[mat][1024][512] bf16: cols 0-255 hi, 256-511 lo.
struct CvtW6 { const float* src[4]; u16* dst; };
__global__ void k6_cvtw(CvtW6 a){
  int g = blockIdx.x * 256 + threadIdx.x;          // one per float4, 4*65536 total
  int mat = g >> 16;
  int rem = g & 65535;
  int row = rem >> 6, c4 = rem & 63;
  f32x4 v = *(const f32x4*)(a.src[mat] + (size_t)row * HDIM + c4 * 4);
  u16x4 hi = { f2b(v[0]), f2b(v[1]), f2b(v[2]), f2b(v[3]) };
  f32x4 r = { v[0] - b2f(hi[0]), v[1] - b2f(hi[1]), v[2] - b2f(hi[2]), v[3] - b2f(hi[3]) };
  u16x4 lo = { f2b(r[0]), f2b(r[1]), f2b(r[2]), f2b(r[3]) };
  u16* base = a.dst + (size_t)mat * GDIM * KD + (size_t)row * KD;
  *(u16x4*)(base + c4 * 4) = hi;
  *(u16x4*)(base + HDIM + c4 * 4) = lo;
}

// ---------------- bias sums ----------------
struct Bias6 { const float* a[4]; const float* b[4]; float* d[4]; };
__global__ void k6_bias(Bias6 z){
  int k = blockIdx.x, i = threadIdx.x;
  z.d[k][i] = z.a[k][i] + z.b[k][i];
}

// ---------------- embedding gather + bf16 cast ----------------
__global__ void k6_embed(const int* __restrict__ text, const float* __restrict__ emb,
                         u16* __restrict__ xbf){
  int row = blockIdx.x;
  int t = threadIdx.x;
  if (t >= 75) return;
  int tok = text[row];
  f32x4 v = *(const f32x4*)(emb + (size_t)tok * EDIM + t * 4);
  u16x4 o = { f2b(v[0]), f2b(v[1]), f2b(v[2]), f2b(v[3]) };
  *(u16x4*)(xbf + (size_t)row * ELDA + t * 4) = o;
}

// ---------------- chunked MFMA GEMM: xg_chunk = A @ W^T + bias (fp32 out) ----------------
// Processes rows (b, t) with t in [tb_z, tb_z+TC). A rows live at b*512 + t.
struct Gemm6 {
  const u16* A; long lda; int K, KT;
  const u16* W0; const u16* W1; long ldw;
  const float* bias0; const float* bias1;
  float* out;            // [2][64][TC][1024]
  int tb0, tb1;
};
__global__ __launch_bounds__(256, 2) void k6_gemm(Gemm6 g){
  const int bm = blockIdx.x, bn = blockIdx.y, z = blockIdx.z;
  const u16* W = z ? g.W1 : g.W0;
  const float* bias = z ? g.bias1 : g.bias0;
  const int tbase = z ? g.tb1 : g.tb0;
  float* outp = g.out + (size_t)z * BATCH * TC * GDIM;
  const int tid = threadIdx.x;
  const int l = tid & 63, l15 = l & 15, lq = l >> 4;
  const int wid = tid >> 6, wm = wid >> 1, wn = wid & 1;

  __shared__ u16 At[2][128 * 40];
  __shared__ u16 Bt[2][128 * 40];

  f32x4 acc[4][4];
#pragma unroll
  for (int i = 0; i < 4; ++i)
#pragma unroll
    for (int j = 0; j < 4; ++j) acc[i][j] = (f32x4){0.f, 0.f, 0.f, 0.f};

  u16x4 alo[2], ahi[2], blo[2], bhi[2];

  auto LOAD = [&](int kt){
#pragma unroll
    for (int c = 0; c < 2; ++c){
      int idx = c * 256 + tid;
      int row = idx >> 2, seg = idx & 3;
      int k0 = kt * 32 + seg * 8;
      int gm = bm * 128 + row;
      size_t arow = (size_t)(gm >> 7) * TSEQ + tbase + (gm & 127);
      if (k0 + 8 <= g.K){
        const u16* p = g.A + arow * g.lda + k0;
        alo[c] = *(const u16x4*)p; ahi[c] = *(const u16x4*)(p + 4);
      } else {
        u16 tmp[8];
#pragma unroll
        for (int e = 0; e < 8; ++e){
          int k = k0 + e;
          tmp[e] = (k < g.K) ? g.A[arow * g.lda + k] : (u16)0;
        }
        alo[c] = (u16x4){tmp[0], tmp[1], tmp[2], tmp[3]};
        ahi[c] = (u16x4){tmp[4], tmp[5], tmp[6], tmp[7]};
      }
      int gn = bn * 128 + row;
      if (k0 + 8 <= g.K){
        const u16* p = W + (size_t)gn * g.ldw + k0;
        blo[c] = *(const u16x4*)p; bhi[c] = *(const u16x4*)(p + 4);
      } else {
        u16 tmp[8];
#pragma unroll
        for (int e = 0; e < 8; ++e){
          int k = k0 + e;
          tmp[e] = (k < g.K) ? W[(size_t)gn * g.ldw + k] : (u16)0;
        }
        blo[c] = (u16x4){tmp[0], tmp[1], tmp[2], tmp[3]};
        bhi[c] = (u16x4){tmp[4], tmp[5], tmp[6], tmp[7]};
      }
    }
  };
  auto STORE = [&](int buf){
#pragma unroll
    for (int c = 0; c < 2; ++c){
      int idx = c * 256 + tid;
      int row = idx >> 2, seg = idx & 3;
      *(u16x4*)&At[buf][row * 40 + seg * 8] = alo[c];
      *(u16x4*)&At[buf][row * 40 + seg * 8 + 4] = ahi[c];
      *(u16x4*)&Bt[buf][row * 40 + seg * 8] = blo[c];
      *(u16x4*)&Bt[buf][row * 40 + seg * 8 + 4] = bhi[c];
    }
  };

  LOAD(0); STORE(0); __syncthreads();
  for (int kt = 0; kt < g.KT; ++kt){
    int cur = kt & 1;
    bool more = (kt + 1 < g.KT);
    if (more) LOAD(kt + 1);
    bf16x8 a[4], b[4];
#pragma unroll
    for (int mi = 0; mi < 4; ++mi)
      a[mi] = *(const bf16x8*)&At[cur][(wm * 64 + mi * 16 + l15) * 40 + lq * 8];
#pragma unroll
    for (int ni = 0; ni < 4; ++ni)
      b[ni] = *(const bf16x8*)&Bt[cur][(wn * 64 + ni * 16 + l15) * 40 + lq * 8];
#pragma unroll
    for (int mi = 0; mi < 4; ++mi)
#pragma unroll
      for (int ni = 0; ni < 4; ++ni)
        acc[mi][ni] = mfma16(a[mi], b[ni], acc[mi][ni]);
    if (more) STORE(cur ^ 1);
    __syncthreads();
  }

#pragma unroll
  for (int mi = 0; mi < 4; ++mi){
#pragma unroll
    for (int ni = 0; ni < 4; ++ni){
      int gn = bn * 128 + wn * 64 + ni * 16 + l15;
      float bs = bias[gn];
#pragma unroll
      for (int r = 0; r < 4; ++r){
        int gm = bm * 128 + wm * 64 + mi * 16 + lq * 4 + r;
        outp[(size_t)gm * GDIM + gn] = acc[mi][ni][r] + bs;
      }
    }
  }
}

// ---------------- recurrent LSTM kernel (chunked, compensated weights) ----------------
// grid = 8: (dir = bx&1, batch-block = bx>>1). 512 thr = 8 waves.
// wave w owns gate tiles (q*16 + 2w + th), q=0..3, th=0..1 -> slots s=q*2+th.
// Whh2 [1024][512] = [hi | lo]: slot 0 in LDS (swizzled), slots 1..7 streamed (ring-2).
// K-loop kc=0..15; A-operand (h) re-read from hbuf at kc&7. xg fp32. h bf16 + error feedback.
__global__ __launch_bounds__(512, 2)
void k6_rec(const float* __restrict__ xgc,   // [2][64][TC][1024] fp32
            const u16* __restrict__ whhL,    // [2][1024][512] bf16 (hi|lo), this layer
            u16* __restrict__ y,             // layer0 out: [64][512][512] bf16
            float* __restrict__ hid,         // final hidden: [64][512] fp32
            float* __restrict__ stc, float* __restrict__ stef, u16* __restrict__ sth,
            int tb0, int tb1, int first, int write_y, int write_hid)
{
  const int dir = blockIdx.x & 1;
  const int b0  = (blockIdx.x >> 1) << 4;
  const int tid = threadIdx.x;
  const int w   = tid >> 6;
  const int l   = tid & 63;
  const int l15 = l & 15;
  const int lq  = l >> 4;
  const int rev = dir;

  __shared__ u16 hbuf[16 * 256];          // 8KB, xor-swizzled
  __shared__ u16 ws1[8 * 16 * KD];        // 128KB: slot-0 weights per wave, swizzled

  const u16* whhd = whhL + (size_t)dir * GDIM * KD;

  int tn16[8];
#pragma unroll
  for (int s = 0; s < 8; ++s) tn16[s] = ((s >> 1) * 16 + 2 * w + (s & 1)) * 16;

  // fill LDS slot 0: 16 rows x 1024B per wave, row-keyed xor swizzle
  {
    const int tb = tn16[0];
    char* wreg = (char*)ws1 + w * 16384;
#pragma unroll
    for (int r = 0; r < 16; ++r){
      bf16x8 v = *(const bf16x8*)(whhd + (size_t)(tb + r) * KD + l * 8);
      *(bf16x8*)(wreg + r * 1024 + ((l * 16) ^ ((r & 7) << 4))) = v;
    }
  }

  const u16* sb[7];
#pragma unroll
  for (int ss = 0; ss < 7; ++ss)
    sb[ss] = whhd + (size_t)(tn16[1 + ss] + l15) * KD + lq * 8;

  int koff[8];
#pragma unroll
  for (int kc = 0; kc < 8; ++kc) koff[kc] = (kc * 64 + lq * 16) ^ ((l15 & 7) << 4);
  const int aoff = l15 * 512;
  const char* hbp = (const char*)hbuf;
  const char* wsp = (const char*)ws1 + w * 16384 + l15 * 1024;

  float cst[8], ef[8], hregf[8];
  u16 hreg[8];

  // init / restore state
  if (first){
    *(f32x4*)((char*)hbuf + tid * 16) = (f32x4){0.f, 0.f, 0.f, 0.f};
#pragma unroll
    for (int i = 0; i < 8; ++i){ cst[i] = 0.f; ef[i] = 0.f; hregf[i] = 0.f; hreg[i] = 0; }
  } else {
#pragma unroll
    for (int th = 0; th < 2; ++th)
#pragma unroll
      for (int r = 0; r < 4; ++r){
        const int idx = th * 4 + r;
        const int m = lq * 4 + r;
        const int j = 32 * w + th * 16 + l15;
        const size_t si = ((size_t)(dir * BATCH + b0 + m)) * HDIM + j;
        cst[idx] = stc[si]; ef[idx] = stef[si];
        u16 hv = sth[si]; hreg[idx] = hv; hregf[idx] = 0.f;
        *(u16*)((char*)hbuf + m * 512 + ((2 * j) ^ ((m & 7) << 4))) = hv;
      }
  }

  size_t xrow[4];
  const int tt0 = rev ? (TC - 1) : 0;
#pragma unroll
  for (int r = 0; r < 4; ++r)
    xrow[r] = ((size_t)dir * BATCH + b0 + lq * 4 + r) * (size_t)(TC * GDIM)
            + (size_t)tt0 * GDIM + l15;
  const long xstep = rev ? -(long)GDIM : (long)GDIM;

#pragma unroll 1
  for (int t = 0; t < TC; ++t){
    const int te = rev ? (tb1 + TC - 1 - t) : (tb0 + t);
    __syncthreads();   // (a) h writes from prev step / init visible

    float xgv[8][4];
#pragma unroll
    for (int s = 0; s < 8; ++s)
#pragma unroll
      for (int r = 0; r < 4; ++r) xgv[s][r] = xgc[xrow[r] + tn16[s]];

    f32x4 acc[8];
#pragma unroll
    for (int s = 0; s < 8; ++s) acc[s] = (f32x4){0.f, 0.f, 0.f, 0.f};

    bf16x8 rb[2][7];
#pragma unroll
    for (int pk = 0; pk < 2; ++pk)
#pragma unroll
      for (int ss = 0; ss < 7; ++ss) rb[pk][ss] = *(const bf16x8*)(sb[ss] + pk * 32);

#pragma unroll
    for (int kc = 0; kc < 16; ++kc){
      bf16x8 af = *(const bf16x8*)(hbp + aoff + koff[kc & 7]);
      bf16x8 w0 = *(const bf16x8*)(wsp + ((kc * 64 + lq * 16) ^ ((l15 & 7) << 4)));
      bf16x8 c1 = rb[kc & 1][0], c2 = rb[kc & 1][1], c3 = rb[kc & 1][2];
      bf16x8 c4 = rb[kc & 1][3], c5 = rb[kc & 1][4], c6 = rb[kc & 1][5], c7 = rb[kc & 1][6];
      if (kc + 2 < 16){
#pragma unroll
        for (int ss = 0; ss < 7; ++ss)
          rb[kc & 1][ss] = *(const bf16x8*)(sb[ss] + (kc + 2) * 32);
      }
      acc[0] = mfma16(af, w0, acc[0]);
      acc[1] = mfma16(af, c1, acc[1]);
      acc[2] = mfma16(af, c2, acc[2]);
      acc[3] = mfma16(af, c3, acc[3]);
      acc[4] = mfma16(af, c4, acc[4]);
      acc[5] = mfma16(af, c5, acc[5]);
      acc[6] = mfma16(af, c6, acc[6]);
      acc[7] = mfma16(af, c7, acc[7]);
    }

    __syncthreads();   // (b) all h reads done before overwriting

#pragma unroll
    for (int th = 0; th < 2; ++th){
#pragma unroll
      for (int r = 0; r < 4; ++r){
        const int idx = th * 4 + r;
        float gi = acc[0 + th][r] + xgv[0 + th][r];
        float gf = acc[2 + th][r] + xgv[2 + th][r];
        float gg = acc[4 + th][r] + xgv[4 + th][r];
        float go = acc[6 + th][r] + xgv[6 + th][r];
        float c = sigm(gf) * cst[idx] + sigm(gi) * tanh_(gg);
        cst[idx] = c;
        float h = sigm(go) * tanh_(c);
        hregf[idx] = h;
        float hq = h + ef[idx];
        u16 hb16 = f2b(hq);
        ef[idx] = hq - b2f(hb16);
        hreg[idx] = hb16;
        const int m = lq * 4 + r;
        const int j = 32 * w + th * 16 + l15;
        *(u16*)((char*)hbuf + m * 512 + ((2 * j) ^ ((m & 7) << 4))) = hb16;
        if (write_y)
          y[(((size_t)(b0 + m)) * TSEQ + te) * 512 + dir * 256 + j] = hb16;
      }
    }

#pragma unroll
    for (int r = 0; r < 4; ++r) xrow[r] += xstep;
  }

  // save state / final hidden
#pragma unroll
  for (int th = 0; th < 2; ++th)
#pragma unroll
    for (int r = 0; r < 4; ++r){
      const int idx = th * 4 + r;
      const int m = lq * 4 + r;
      const int j = 32 * w + th * 16 + l15;
      const size_t si = ((size_t)(dir * BATCH + b0 + m)) * HDIM + j;
      stc[si] = cst[idx]; stef[si] = ef[idx]; sth[si] = hreg[idx];
      if (write_hid)
        hid[((size_t)(b0 + m)) * 512 + dir * 256 + j] = hregf[idx];
    }
}

// ---------------- FC in pure fp32 ----------------
__global__ void k6_fc(const float* __restrict__ hid, const float* __restrict__ fcW,
                      const float* __restrict__ fcb, float* __restrict__ out){
  const int b = blockIdx.y;
  const int o = blockIdx.x * 64 + threadIdx.x;
  __shared__ float hs[512];
#pragma unroll
  for (int i = 0; i < 8; ++i) hs[threadIdx.x * 8 + i] = hid[b * 512 + threadIdx.x * 8 + i];
  __syncthreads();
  const f32x4* w4 = (const f32x4*)(fcW + (size_t)o * 512);
  const f32x4* h4 = (const f32x4*)hs;
  float s = 0.f;
#pragma unroll 8
  for (int i = 0; i < 128; ++i){
    f32x4 a = h4[i], bq = w4[i];
    s += a[0] * bq[0] + a[1] * bq[1] + a[2] * bq[2] + a[3] * bq[3];
  }
  out[b * 512 + o] = s + fcb[o];
}

// ---------------- host launch ----------------
extern "C" void kernel_launch(void* const* d_in, const int* in_sizes, int n_in,
                              void* d_out, int out_size, void* d_ws, size_t ws_size,
                              hipStream_t stream)
{
  (void)in_sizes; (void)n_in; (void)out_size; (void)ws_size;
  const int*   text = (const int*)d_in[0];
  const float* emb  = (const float*)d_in[1];
  const float* Wih[4] = {(const float*)d_in[2], (const float*)d_in[6], (const float*)d_in[10], (const float*)d_in[14]};
  const float* Whh[4] = {(const float*)d_in[3], (const float*)d_in[7], (const float*)d_in[11], (const float*)d_in[15]};
  const float* bih[4] = {(const float*)d_in[4], (const float*)d_in[8], (const float*)d_in[12], (const float*)d_in[16]};
  const float* bhh[4] = {(const float*)d_in[5], (const float*)d_in[9], (const float*)d_in[13], (const float*)d_in[17]};
  const float* fcW = (const float*)d_in[18];
  const float* fcb = (const float*)d_in[19];

  char* ws = (char*)d_ws;
  size_t off = 0;
  auto alloc = [&](size_t bytes) -> void* {
    void* p = ws + off;
    off += (bytes + 255) & ~(size_t)255;
    return p;
  };

  u16*   xbf    = (u16*)alloc((size_t)BATCH * TSEQ * ELDA * 2);          // 19.9 MB
  u16*   wihb0f = (u16*)alloc((size_t)GDIM * 300 * 2);
  u16*   wihb0b = (u16*)alloc((size_t)GDIM * 300 * 2);
  u16*   wihb1f = (u16*)alloc((size_t)GDIM * 512 * 2);
  u16*   wihb1b = (u16*)alloc((size_t)GDIM * 512 * 2);
  u16*   whh2   = (u16*)alloc((size_t)4 * GDIM * KD * 2);                // 4.2 MB hi|lo
  float* bsum   = (float*)alloc((size_t)4 * GDIM * 4);
  float* xgc    = (float*)alloc((size_t)2 * BATCH * TC * GDIM * 4);      // 67.1 MB
  u16*   y0     = (u16*)alloc((size_t)BATCH * TSEQ * 512 * 2);           // 33.6 MB
  float* stc    = (float*)alloc((size_t)2 * BATCH * HDIM * 4);
  float* stef   = (float*)alloc((size_t)2 * BATCH * HDIM * 4);
  u16*   sth    = (u16*)alloc((size_t)2 * BATCH * HDIM * 2);
  float* hidf   = (float*)alloc((size_t)BATCH * 512 * 4);

  // --- Wih -> bf16 ---
  Cvt6 ca;
  ca.src[0] = Wih[0]; ca.dst[0] = wihb0f;
  ca.src[1] = Wih[1]; ca.dst[1] = wihb0b;
  ca.src[2] = Wih[2]; ca.dst[2] = wihb1f;
  ca.src[3] = Wih[3]; ca.dst[3] = wihb1b;
  {
    int cnt4[4] = {76800, 76800, 131072, 131072};
    ca.cum[0] = 0;
    for (int i = 0; i < 4; ++i) ca.cum[i + 1] = ca.cum[i] + cnt4[i];
  }
  k6_cvt<<<dim3((415744 + 255) / 256), dim3(256), 0, stream>>>(ca);

  // --- Whh -> compensated hi|lo planes ---
  CvtW6 cw;
  for (int k = 0; k < 4; ++k) cw.src[k] = Whh[k];
  cw.dst = whh2;
  k6_cvtw<<<dim3(1024), dim3(256), 0, stream>>>(cw);

  Bias6 ba;
  for (int k = 0; k < 4; ++k){ ba.a[k] = bih[k]; ba.b[k] = bhh[k]; ba.d[k] = bsum + k * GDIM; }
  k6_bias<<<dim3(4), dim3(1024), 0, stream>>>(ba);

  k6_embed<<<dim3(BATCH * TSEQ), dim3(128), 0, stream>>>(text, emb, xbf);

  // --- layer 0: chunked gemm + recurrence ---
  for (int c = 0; c < NC; ++c){
    Gemm6 g0;
    g0.A = xbf; g0.lda = ELDA; g0.K = 300; g0.KT = 10;
    g0.W0 = wihb0f; g0.W1 = wihb0b; g0.ldw = 300;
    g0.bias0 = bsum; g0.bias1 = bsum + GDIM;
    g0.out = xgc; g0.tb0 = c * TC; g0.tb1 = (TSEQ - TC) - c * TC;
    k6_gemm<<<dim3(64, 8, 2), dim3(256), 0, stream>>>(g0);
    k6_rec<<<dim3(8), dim3(512), 0, stream>>>(xgc, whh2, y0, hidf,
        stc, stef, sth, c * TC, (TSEQ - TC) - c * TC, (c == 0) ? 1 : 0, 1, 0);
  }

  // --- layer 1: chunked gemm + recurrence ---
  for (int c = 0; c < NC; ++c){
    Gemm6 g1;
    g1.A = y0; g1.lda = 512; g1.K = 512; g1.KT = 16;
    g1.W0 = wihb1f; g1.W1 = wihb1b; g1.ldw = 512;
    g1.bias0 = bsum + 2 * GDIM; g1.bias1 = bsum + 3 * GDIM;
    g1.out = xgc; g1.tb0 = c * TC; g1.tb1 = (TSEQ - TC) - c * TC;
    k6_gemm<<<dim3(64, 8, 2), dim3(256), 0, stream>>>(g1);
    k6_rec<<<dim3(8), dim3(512), 0, stream>>>(xgc, whh2 + (size_t)2 * GDIM * KD, y0, hidf,
        stc, stef, sth, c * TC, (TSEQ - TC) - c * TC, (c == 0) ? 1 : 0, 0, (c == NC - 1) ? 1 : 0);
  }

  // --- FC in fp32 from fp32 weights ---
  k6_fc<<<dim3(8, 64), dim3(64), 0, stream>>>(hidf, fcW, fcb, (float*)d_out);
}